// Round 16
// baseline (795.120 us; speedup 1.0000x reference)
//
#include <hip/hip_runtime.h>
#include <hip/hip_bf16.h>
#include <math.h>

#define T_TOK 2048
#define HID   2048
#define NE    32
#define DF    1024
#define DSZ   4096
#define TOPK  6
#define NGRP  8
#define TOPKG 4
#define RSCALE 2.5f
#define EXT_E 36            // 32 routed + 4 shared pseudo-experts
#define NSLOT 20480         // 12288 routed + 8192 shared slots

typedef __attribute__((ext_vector_type(8))) short short8;
typedef __attribute__((ext_vector_type(4))) float f32x4;

typedef __attribute__((address_space(1))) const void gv1;
typedef __attribute__((address_space(3))) void lv3;

static __device__ __forceinline__ void gload16(const void* g, void* l) {
    __builtin_amdgcn_global_load_lds((gv1*)g, (lv3*)l, 16, 0, 0);
}

static __device__ __forceinline__ unsigned short f2b(float f) {
    union { float f; unsigned u; } v; v.f = f;
    unsigned r = v.u + 0x7fffu + ((v.u >> 16) & 1u);
    return (unsigned short)(r >> 16);
}

static __device__ __forceinline__ float b2f(unsigned short b) {
    union { float f; unsigned u; } v; v.u = ((unsigned)b) << 16;
    return v.f;
}

// ---------------- router (one block per token), fused x->bf16 ----------------
__global__ __launch_bounds__(256)
void router_kernel(const float* __restrict__ x, const float* __restrict__ rw,
                   const float* __restrict__ rb,
                   int* __restrict__ tidx, float* __restrict__ tw,
                   int* __restrict__ counts, unsigned short* __restrict__ xb) {
    __shared__ float xs[HID];
    __shared__ float part[256];
    __shared__ float scores[NE];
    __shared__ float sfc[NE];
    int t = blockIdx.x;
    int tid = threadIdx.x;
    for (int i = tid; i < HID / 4; i += 256) {
        ((float4*)xs)[i] = ((const float4*)(x + (size_t)t * HID))[i];
    }
    __syncthreads();
    {
        float4 a = ((const float4*)xs)[tid * 2];
        float4 b = ((const float4*)xs)[tid * 2 + 1];
        short8 o;
        o[0] = (short)f2b(a.x); o[1] = (short)f2b(a.y); o[2] = (short)f2b(a.z); o[3] = (short)f2b(a.w);
        o[4] = (short)f2b(b.x); o[5] = (short)f2b(b.y); o[6] = (short)f2b(b.z); o[7] = (short)f2b(b.w);
        *(short8*)(xb + (size_t)t * HID + tid * 8) = o;
    }
    int e = tid & 31, ch = tid >> 5;
    const float* w = rw + (size_t)e * HID + ch * 256;
    const float* xv = xs + ch * 256;
    float p = 0.f;
    #pragma unroll 8
    for (int k = 0; k < 256; ++k) p += xv[k] * w[k];
    part[tid] = p;
    __syncthreads();
    if (tid < 32) {
        float l = 0.f;
        #pragma unroll
        for (int c = 0; c < 8; ++c) l += part[c * 32 + tid];
        float s = 1.f / (1.f + expf(-l));
        scores[tid] = s;
        sfc[tid] = s + rb[tid];
    }
    __syncthreads();
    if (tid == 0) {
        float gs[NGRP];
        for (int g = 0; g < NGRP; ++g) {
            float v[4];
            for (int i = 0; i < 4; ++i) v[i] = sfc[g * 4 + i];
            int bi = 0;
            for (int i = 1; i < 4; ++i) if (v[i] > v[bi]) bi = i;
            float m1 = v[bi]; v[bi] = -INFINITY;
            int bj = 0;
            for (int i = 1; i < 4; ++i) if (v[i] > v[bj]) bj = i;
            gs[g] = m1 + v[bj];
        }
        bool gsel[NGRP];
        for (int g = 0; g < NGRP; ++g) gsel[g] = false;
        for (int k = 0; k < TOPKG; ++k) {
            int bi = -1; float b = -INFINITY;
            for (int g = 0; g < NGRP; ++g)
                if (!gsel[g] && gs[g] > b) { b = gs[g]; bi = g; }
            gsel[bi] = true;
        }
        float masked[NE];
        for (int i = 0; i < NE; ++i) masked[i] = gsel[i >> 2] ? sfc[i] : 0.0f;
        int sel[TOPK]; float wv[TOPK]; float wsum = 0.f;
        for (int k = 0; k < TOPK; ++k) {
            int bi = -1; float b = -INFINITY;
            for (int i = 0; i < NE; ++i)
                if (masked[i] > b) { b = masked[i]; bi = i; }
            masked[bi] = -INFINITY;
            sel[k] = bi; wv[k] = scores[bi]; wsum += wv[k];
        }
        float inv = RSCALE / (wsum + 1e-20f);
        for (int k = 0; k < TOPK; ++k) {
            tidx[t * TOPK + k] = sel[k];
            tw[t * TOPK + k] = wv[k] * inv;
            atomicAdd(&counts[sel[k]], 1);
        }
    }
}

__global__ void scan_kernel(const int* __restrict__ counts, int* __restrict__ offsets) {
    if (threadIdx.x == 0) {
        int a = 0;
        for (int e2 = 0; e2 < NE; ++e2) { offsets[e2] = a; a += counts[e2]; }
        offsets[NE] = a;                          // = 12288
        for (int j = 1; j <= 4; ++j) offsets[NE + j] = 12288 + j * T_TOK;
    }
}

__global__ void scatter_kernel(const int* __restrict__ tidx, const float* __restrict__ tw,
                               const int* __restrict__ offsets, int* __restrict__ cursors,
                               int* __restrict__ perm, float* __restrict__ pw,
                               int* __restrict__ slot_of) {
    int t = blockIdx.x * blockDim.x + threadIdx.x;
    if (t >= T_TOK) return;
    for (int k = 0; k < TOPK; ++k) {
        int e = tidx[t * TOPK + k];
        int pos = atomicAdd(&cursors[e], 1);
        int slot = offsets[e] + pos;
        perm[slot] = t;
        pw[slot] = tw[t * TOPK + k];
        slot_of[t * TOPK + k] = slot;
    }
    #pragma unroll
    for (int j = 0; j < 4; ++j) {                 // shared pseudo-expert slots
        int slot = 12288 + j * T_TOK + t;
        perm[slot] = t;
        pw[slot] = 1.0f;
    }
}

// ---------------- transpose v4 tile body (round-7-measured), smem passed in ----------------
static __device__ __forceinline__ void transpose_tile64(
        const float* __restrict__ src, unsigned short* __restrict__ dst,
        int rs, int Kd, int k0, int n0, char* smem) {
    float (*tl)[65] = (float(*)[65])smem;
    int t = threadIdx.x;
    int r0 = t >> 4;             // 0..15
    int c4 = (t & 15) * 4;       // 0..60
    #pragma unroll
    for (int p = 0; p < 4; ++p) {
        int r = r0 + p * 16;
        float4 v = *(const float4*)(src + (size_t)(k0 + r) * rs + n0 + c4);
        tl[c4 + 0][r] = v.x;
        tl[c4 + 1][r] = v.y;
        tl[c4 + 2][r] = v.z;
        tl[c4 + 3][r] = v.w;
    }
    __syncthreads();
    int n = t >> 2;              // 0..63
    int kq = (t & 3) * 16;       // 0..48
    unsigned short o[16];
    #pragma unroll
    for (int i = 0; i < 16; ++i) o[i] = f2b(tl[n][kq + i]);
    unsigned short* d = dst + (size_t)(n0 + n) * Kd + k0 + kq;
    *(short8*)(d) = *(short8*)&o[0];
    *(short8*)(d + 8) = *(short8*)&o[8];
}

// ---------------- T(U) standalone: grid(512, 36) ----------------
__global__ __launch_bounds__(256)
void transpose_up_kernel(const float* __restrict__ w_up, const float* __restrict__ sh_up,
                         unsigned short* __restrict__ bufU) {
    __shared__ __align__(16) char smem[16640];
    int z = blockIdx.y;
    const float* src; int rs;
    if (z < NE) { src = w_up + (size_t)z * HID * DF; rs = DF; }
    else        { src = sh_up + (size_t)(z - NE) * DF; rs = DSZ; }
    int tile = blockIdx.x;
    int tn = tile & 15, tk = tile >> 4;           // N=1024: 16, K=2048: 32
    transpose_tile64(src, bufU + (size_t)z * DF * HID, rs, HID, tk * 64, tn * 64, smem);
}

// ---------------- up-GEMM body (round-7-verified single-buffer), smem passed in ----------------
static __device__ void gemm_up_body(int bx, int by, int bz,
                                    const unsigned short* __restrict__ xb,
                                    const unsigned short* __restrict__ bufU,
                                    unsigned short* __restrict__ act,
                                    const int* __restrict__ offsets,
                                    const int* __restrict__ perm,
                                    const float* __restrict__ pw, char* lds) {
    constexpr int K = HID, N = DF;
    char* As = lds;
    char* Bs = lds + 16384;

    int tid = threadIdx.x;
    int lane = tid & 63, wvid = tid >> 6, wr = wvid >> 1, wc = wvid & 1;

    int off = offsets[bz], end = offsets[bz + 1];
    int row0 = off + by * 128;
    if (row0 >= end) return;
    int n0 = bx * 128;

    int lr = lane >> 3;
    int csrc = (((lane & 7) ^ lr) << 4);
    size_t abyte[4], bbyte[4];
    int ldsoff[4];
    const char* Bb = (const char*)bufU + (size_t)bz * ((size_t)N * K * 2);
    #pragma unroll
    for (int p = 0; p < 4; ++p) {
        int r = p * 32 + wvid * 8 + lr;
        int gr = row0 + r;
        if (gr > end - 1) gr = end - 1;
        abyte[p] = (size_t)perm[gr] * (K * 2);
        bbyte[p] = (size_t)(n0 + r) * (K * 2);
        ldsoff[p] = (p * 32 + wvid * 8) * 128;
    }

    f32x4 acc[4][4] = {};
    for (int k0 = 0; k0 < K; k0 += 64) {
        __syncthreads();
        #pragma unroll
        for (int p = 0; p < 4; ++p) {
            gload16((const char*)xb + abyte[p] + k0 * 2 + csrc, As + ldsoff[p]);
            gload16(Bb + bbyte[p] + k0 * 2 + csrc, Bs + ldsoff[p]);
        }
        __syncthreads();
        #pragma unroll
        for (int ks = 0; ks < 2; ++ks) {
            int kg = lane >> 4, r16 = lane & 15;
            short8 af[4], bfr[4];
            #pragma unroll
            for (int m = 0; m < 4; ++m) {
                int r = wr * 64 + m * 16 + r16;
                af[m] = *(const short8*)(As + r * 128 + ((ks * 64 + kg * 16) ^ ((r & 7) << 4)));
            }
            #pragma unroll
            for (int n = 0; n < 4; ++n) {
                int c = wc * 64 + n * 16 + r16;
                bfr[n] = *(const short8*)(Bs + c * 128 + ((ks * 64 + kg * 16) ^ ((c & 7) << 4)));
            }
            #pragma unroll
            for (int m = 0; m < 4; ++m)
                #pragma unroll
                for (int n = 0; n < 4; ++n)
                    acc[m][n] = __builtin_amdgcn_mfma_f32_16x16x32_bf16(af[m], bfr[n], acc[m][n], 0, 0, 0);
        }
    }

    int r16 = lane & 15, rg = lane >> 4;
    #pragma unroll
    for (int m = 0; m < 4; ++m) {
        #pragma unroll
        for (int j = 0; j < 4; ++j) {
            int rr = row0 + wr * 64 + m * 16 + rg * 4 + j;
            if (rr < end) {
                float scale = pw[rr];
                #pragma unroll
                for (int n = 0; n < 4; ++n) {
                    int cc = n0 + wc * 64 + n * 16 + r16;
                    float v = acc[m][n][j];
                    v = v > 0.f ? v * v : 0.f;
                    act[(size_t)rr * N + cc] = f2b(v * scale);
                }
            }
        }
    }
}

// ---------------- merged: up-GEMM (bid%5==0, 4608) + T(D) (18432 tiles) ----------------
// GEMM logical block i = bid/5 lands on XCD (5i)&7; XCD-chunked work map:
// g2 = ((5i)&7)*576 + (i>>3)  (bijective over 4608 = 8 x 576) -> panel-sharers same XCD.
__global__ __launch_bounds__(256, 2)
void gemm_up_tdn_kernel(const unsigned short* __restrict__ xb,
                        const unsigned short* __restrict__ bufU,
                        unsigned short* __restrict__ act,
                        const int* __restrict__ offsets, const int* __restrict__ perm,
                        const float* __restrict__ pw,
                        const float* __restrict__ w_dn, const float* __restrict__ sh_dn,
                        unsigned short* __restrict__ bufD) {
    __shared__ __align__(16) char smem[32768];
    int bid = blockIdx.x;
    if (bid % 5 != 0) {
        int tile = bid - bid / 5 - 1;             // 0..18431
        int tz = tile >> 9;                       // 0..35
        int rem = tile & 511;
        int tn = rem & 31, tk = rem >> 5;         // N=2048: 32, K=1024: 16
        const float* src = (tz < NE) ? (w_dn + (size_t)tz * DF * HID)
                                     : (sh_dn + (size_t)(tz - NE) * DF * HID);
        transpose_tile64(src, bufD + (size_t)tz * HID * DF, HID, DF, tk * 64, tn * 64, smem);
        return;
    }
    int i = bid / 5;                              // 0..4607
    int g2 = ((5 * i) & 7) * 576 + (i >> 3);      // XCD-chunked
    gemm_up_body(g2 & 7, (g2 >> 3) & 15, g2 >> 7, xb, bufU, act, offsets, perm, pw, smem);
}

// ---------------- down-GEMM (1-D grid 9216, XCD-chunked): K=1024, N=2048; C=slotout bf16 ----
// g2 = (bid&7)*1152 + (bid>>3)  (bijective over 9216 = 8 x 1152); bx fastest in g2.
__global__ __launch_bounds__(256, 2)
void gemm_down_kernel(const unsigned short* __restrict__ act, const unsigned short* __restrict__ bufD,
                      unsigned short* __restrict__ slotout, const int* __restrict__ offsets) {
    constexpr int K = DF, N = HID;
    __shared__ __align__(16) char lds[32768];
    char* As = lds;
    char* Bs = lds + 16384;

    int bid = blockIdx.x;
    int g2 = (bid & 7) * 1152 + (bid >> 3);
    int bx = g2 & 15, by = (g2 >> 4) & 15, bz = g2 >> 8;

    int tid = threadIdx.x;
    int lane = tid & 63, wvid = tid >> 6, wr = wvid >> 1, wc = wvid & 1;

    int off = offsets[bz], end = offsets[bz + 1];
    int row0 = off + by * 128;
    if (row0 >= end) return;
    int n0 = bx * 128;

    int lr = lane >> 3;
    int csrc = (((lane & 7) ^ lr) << 4);
    size_t abyte[4], bbyte[4];
    int ldsoff[4];
    const char* Bb = (const char*)bufD + (size_t)bz * ((size_t)N * K * 2);
    #pragma unroll
    for (int p = 0; p < 4; ++p) {
        int r = p * 32 + wvid * 8 + lr;
        int gr = row0 + r;
        if (gr > end - 1) gr = end - 1;
        abyte[p] = (size_t)gr * (K * 2);
        bbyte[p] = (size_t)(n0 + r) * (K * 2);
        ldsoff[p] = (p * 32 + wvid * 8) * 128;
    }

    f32x4 acc[4][4] = {};
    for (int k0 = 0; k0 < K; k0 += 64) {
        __syncthreads();
        #pragma unroll
        for (int p = 0; p < 4; ++p) {
            gload16((const char*)act + abyte[p] + k0 * 2 + csrc, As + ldsoff[p]);
            gload16(Bb + bbyte[p] + k0 * 2 + csrc, Bs + ldsoff[p]);
        }
        __syncthreads();
        #pragma unroll
        for (int ks = 0; ks < 2; ++ks) {
            int kg = lane >> 4, r16 = lane & 15;
            short8 af[4], bfr[4];
            #pragma unroll
            for (int m = 0; m < 4; ++m) {
                int r = wr * 64 + m * 16 + r16;
                af[m] = *(const short8*)(As + r * 128 + ((ks * 64 + kg * 16) ^ ((r & 7) << 4)));
            }
            #pragma unroll
            for (int n = 0; n < 4; ++n) {
                int c = wc * 64 + n * 16 + r16;
                bfr[n] = *(const short8*)(Bs + c * 128 + ((ks * 64 + kg * 16) ^ ((c & 7) << 4)));
            }
            #pragma unroll
            for (int m = 0; m < 4; ++m)
                #pragma unroll
                for (int n = 0; n < 4; ++n)
                    acc[m][n] = __builtin_amdgcn_mfma_f32_16x16x32_bf16(af[m], bfr[n], acc[m][n], 0, 0, 0);
        }
    }

    int r16 = lane & 15, rg = lane >> 4;
    #pragma unroll
    for (int m = 0; m < 4; ++m) {
        #pragma unroll
        for (int j = 0; j < 4; ++j) {
            int rr = row0 + wr * 64 + m * 16 + rg * 4 + j;
            if (rr < end) {
                #pragma unroll
                for (int n = 0; n < 4; ++n) {
                    int cc = n0 + wc * 64 + n * 16 + r16;
                    slotout[(size_t)rr * N + cc] = f2b(acc[m][n][j]);
                }
            }
        }
    }
}

// ---------------- combine: out[t] = sum of 6 routed + 4 shared slot rows (bf16 in, f32 out) ----
__global__ void combine_kernel(const unsigned short* __restrict__ slotout,
                               const int* __restrict__ slot_of,
                               float* __restrict__ out) {
    int t = blockIdx.x, tid = threadIdx.x;
    int s[10];
    #pragma unroll
    for (int k = 0; k < TOPK; ++k) s[k] = slot_of[t * TOPK + k];
    #pragma unroll
    for (int j = 0; j < 4; ++j) s[TOPK + j] = 12288 + j * T_TOK + t;
    int c = tid * 8;
    float a[8] = {0.f, 0.f, 0.f, 0.f, 0.f, 0.f, 0.f, 0.f};
    #pragma unroll
    for (int k = 0; k < 10; ++k) {
        short8 v = *(const short8*)(slotout + (size_t)s[k] * HID + c);
        #pragma unroll
        for (int i = 0; i < 8; ++i) a[i] += b2f((unsigned short)v[i]);
    }
    *(float4*)(out + (size_t)t * HID + c) = make_float4(a[0], a[1], a[2], a[3]);
    *(float4*)(out + (size_t)t * HID + c + 4) = make_float4(a[4], a[5], a[6], a[7]);
}

extern "C" void kernel_launch(void* const* d_in, const int* in_sizes, int n_in,
                              void* d_out, int out_size, void* d_ws, size_t ws_size,
                              hipStream_t stream) {
    const float* x     = (const float*)d_in[0];
    const float* rw    = (const float*)d_in[1];
    const float* rb    = (const float*)d_in[2];
    const float* w_up  = (const float*)d_in[3];
    const float* w_dn  = (const float*)d_in[4];
    const float* sh_up = (const float*)d_in[5];
    const float* sh_dn = (const float*)d_in[6];
    float* out = (float*)d_out;
    char* ws = (char*)d_ws;

    int*   counts  = (int*)(ws);
    int*   cursors = (int*)(ws + 128);
    int*   offsets = (int*)(ws + 256);            // 37 ints
    int*   tidx    = (int*)(ws + 1024);           // 12288 int
    float* tw      = (float*)(ws + 50176);        // 12288 f32
    int*   slot_of = (int*)(ws + 99328);          // 12288 int
    int*   perm    = (int*)(ws + 148480);         // 20480 int
    float* pw      = (float*)(ws + 230400);       // 20480 f32
    unsigned short* xb   = (unsigned short*)(ws + 312320);     // [2048][2048] bf16 (8.4MB)
    unsigned short* act  = (unsigned short*)(ws + 8700928);    // [20480][1024] bf16 (41.9MB)
    unsigned short* bufU = (unsigned short*)(ws + 50643968);   // 36x[1024][2048] bf16 (151MB)
    unsigned short* bufD = (unsigned short*)(ws + 201638912);  // 36x[2048][1024] bf16 (151MB)
    unsigned short* slotout = (unsigned short*)(ws + 352633856); // [20480][2048] bf16 (84MB)

    hipMemsetAsync(ws, 0, 256, stream);  // counts + cursors

    router_kernel<<<T_TOK, 256, 0, stream>>>(x, rw, rb, tidx, tw, counts, xb);
    scan_kernel<<<1, 64, 0, stream>>>(counts, offsets);
    scatter_kernel<<<(T_TOK + 255) / 256, 256, 0, stream>>>(tidx, tw, offsets, cursors,
                                                            perm, pw, slot_of);

    // T(U) standalone
    transpose_up_kernel<<<dim3(512, EXT_E), 256, 0, stream>>>(w_up, sh_up, bufU);

    // up-GEMM (4608, bid%5==0, XCD-chunked) packed with T(D) (18432 tiles)
    gemm_up_tdn_kernel<<<23040, 256, 0, stream>>>(xb, bufU, act, offsets, perm, pw,
                                                  w_dn, sh_dn, bufD);

    // down-GEMM (1-D, XCD-chunked)
    gemm_down_kernel<<<9216, 256, 0, stream>>>(act, bufD, slotout, offsets);

    combine_kernel<<<T_TOK, 256, 0, stream>>>(slotout, slot_of, out);
}

// Round 17
// 638.891 us; speedup vs baseline: 1.2445x; 1.2445x over previous
//
#include <hip/hip_runtime.h>
#include <hip/hip_bf16.h>
#include <math.h>

#define T_TOK 2048
#define HID   2048
#define NE    32
#define DF    1024
#define DSZ   4096
#define TOPK  6
#define NGRP  8
#define TOPKG 4
#define RSCALE 2.5f
#define EXT_E 36            // 32 routed + 4 shared pseudo-experts
#define ZSPLIT 12           // pipeline split point for T(U)/up-GEMM

typedef __attribute__((ext_vector_type(8))) short short8;
typedef __attribute__((ext_vector_type(4))) float f32x4;

typedef __attribute__((address_space(1))) const void gv1;
typedef __attribute__((address_space(3))) void lv3;

static __device__ __forceinline__ void gload16(const void* g, void* l) {
    __builtin_amdgcn_global_load_lds((gv1*)g, (lv3*)l, 16, 0, 0);
}

static __device__ __forceinline__ unsigned short f2b(float f) {
    union { float f; unsigned u; } v; v.f = f;
    unsigned r = v.u + 0x7fffu + ((v.u >> 16) & 1u);
    return (unsigned short)(r >> 16);
}

static __device__ __forceinline__ float b2f(unsigned short b) {
    union { float f; unsigned u; } v; v.u = ((unsigned)b) << 16;
    return v.f;
}

// ---------------- router (one block per token), fused x->bf16 ----------------
__global__ __launch_bounds__(256)
void router_kernel(const float* __restrict__ x, const float* __restrict__ rw,
                   const float* __restrict__ rb,
                   int* __restrict__ tidx, float* __restrict__ tw,
                   int* __restrict__ counts, unsigned short* __restrict__ xb) {
    __shared__ float xs[HID];
    __shared__ float part[256];
    __shared__ float scores[NE];
    __shared__ float sfc[NE];
    int t = blockIdx.x;
    int tid = threadIdx.x;
    for (int i = tid; i < HID / 4; i += 256) {
        ((float4*)xs)[i] = ((const float4*)(x + (size_t)t * HID))[i];
    }
    __syncthreads();
    {
        float4 a = ((const float4*)xs)[tid * 2];
        float4 b = ((const float4*)xs)[tid * 2 + 1];
        short8 o;
        o[0] = (short)f2b(a.x); o[1] = (short)f2b(a.y); o[2] = (short)f2b(a.z); o[3] = (short)f2b(a.w);
        o[4] = (short)f2b(b.x); o[5] = (short)f2b(b.y); o[6] = (short)f2b(b.z); o[7] = (short)f2b(b.w);
        *(short8*)(xb + (size_t)t * HID + tid * 8) = o;
    }
    int e = tid & 31, ch = tid >> 5;
    const float* w = rw + (size_t)e * HID + ch * 256;
    const float* xv = xs + ch * 256;
    float p = 0.f;
    #pragma unroll 8
    for (int k = 0; k < 256; ++k) p += xv[k] * w[k];
    part[tid] = p;
    __syncthreads();
    if (tid < 32) {
        float l = 0.f;
        #pragma unroll
        for (int c = 0; c < 8; ++c) l += part[c * 32 + tid];
        float s = 1.f / (1.f + expf(-l));
        scores[tid] = s;
        sfc[tid] = s + rb[tid];
    }
    __syncthreads();
    if (tid == 0) {
        float gs[NGRP];
        for (int g = 0; g < NGRP; ++g) {
            float v[4];
            for (int i = 0; i < 4; ++i) v[i] = sfc[g * 4 + i];
            int bi = 0;
            for (int i = 1; i < 4; ++i) if (v[i] > v[bi]) bi = i;
            float m1 = v[bi]; v[bi] = -INFINITY;
            int bj = 0;
            for (int i = 1; i < 4; ++i) if (v[i] > v[bj]) bj = i;
            gs[g] = m1 + v[bj];
        }
        bool gsel[NGRP];
        for (int g = 0; g < NGRP; ++g) gsel[g] = false;
        for (int k = 0; k < TOPKG; ++k) {
            int bi = -1; float b = -INFINITY;
            for (int g = 0; g < NGRP; ++g)
                if (!gsel[g] && gs[g] > b) { b = gs[g]; bi = g; }
            gsel[bi] = true;
        }
        float masked[NE];
        for (int i = 0; i < NE; ++i) masked[i] = gsel[i >> 2] ? sfc[i] : 0.0f;
        int sel[TOPK]; float wv[TOPK]; float wsum = 0.f;
        for (int k = 0; k < TOPK; ++k) {
            int bi = -1; float b = -INFINITY;
            for (int i = 0; i < NE; ++i)
                if (masked[i] > b) { b = masked[i]; bi = i; }
            masked[bi] = -INFINITY;
            sel[k] = bi; wv[k] = scores[bi]; wsum += wv[k];
        }
        float inv = RSCALE / (wsum + 1e-20f);
        for (int k = 0; k < TOPK; ++k) {
            tidx[t * TOPK + k] = sel[k];
            tw[t * TOPK + k] = wv[k] * inv;
            atomicAdd(&counts[sel[k]], 1);
        }
    }
}

__global__ void scan_kernel(const int* __restrict__ counts, int* __restrict__ offsets) {
    if (threadIdx.x == 0) {
        int a = 0;
        for (int e2 = 0; e2 < NE; ++e2) { offsets[e2] = a; a += counts[e2]; }
        offsets[NE] = a;                          // = 12288
        for (int j = 1; j <= 4; ++j) offsets[NE + j] = 12288 + j * T_TOK;
    }
}

__global__ void scatter_kernel(const int* __restrict__ tidx, const float* __restrict__ tw,
                               const int* __restrict__ offsets, int* __restrict__ cursors,
                               int* __restrict__ perm, float* __restrict__ pw,
                               int* __restrict__ slot_of) {
    int t = blockIdx.x * blockDim.x + threadIdx.x;
    if (t >= T_TOK) return;
    for (int k = 0; k < TOPK; ++k) {
        int e = tidx[t * TOPK + k];
        int pos = atomicAdd(&cursors[e], 1);
        int slot = offsets[e] + pos;
        perm[slot] = t;
        pw[slot] = tw[t * TOPK + k];
        slot_of[t * TOPK + k] = slot;
    }
    #pragma unroll
    for (int j = 0; j < 4; ++j) {                 // shared pseudo-expert slots
        int slot = 12288 + j * T_TOK + t;
        perm[slot] = t;
        pw[slot] = 1.0f;
    }
}

// ---------------- transpose v4 tile body (round-7-measured), smem passed in ----------------
static __device__ __forceinline__ void transpose_tile64(
        const float* __restrict__ src, unsigned short* __restrict__ dst,
        int rs, int Kd, int k0, int n0, char* smem) {
    float (*tl)[65] = (float(*)[65])smem;
    int t = threadIdx.x;
    int r0 = t >> 4;             // 0..15
    int c4 = (t & 15) * 4;       // 0..60
    #pragma unroll
    for (int p = 0; p < 4; ++p) {
        int r = r0 + p * 16;
        float4 v = *(const float4*)(src + (size_t)(k0 + r) * rs + n0 + c4);
        tl[c4 + 0][r] = v.x;
        tl[c4 + 1][r] = v.y;
        tl[c4 + 2][r] = v.z;
        tl[c4 + 3][r] = v.w;
    }
    __syncthreads();
    int n = t >> 2;              // 0..63
    int kq = (t & 3) * 16;       // 0..48
    unsigned short o[16];
    #pragma unroll
    for (int i = 0; i < 16; ++i) o[i] = f2b(tl[n][kq + i]);
    unsigned short* d = dst + (size_t)(n0 + n) * Kd + k0 + kq;
    *(short8*)(d) = *(short8*)&o[0];
    *(short8*)(d + 8) = *(short8*)&o[8];
}

// T(U) tile for expert z, tile index 0..511 (tn = t&15, tk = t>>4)
static __device__ __forceinline__ void tu_tile(int z, int tile,
                                               const float* __restrict__ w_up,
                                               const float* __restrict__ sh_up,
                                               unsigned short* __restrict__ bufU, char* smem) {
    const float* src; int rs;
    if (z < NE) { src = w_up + (size_t)z * HID * DF; rs = DF; }
    else        { src = sh_up + (size_t)(z - NE) * DF; rs = DSZ; }
    int tn = tile & 15, tk = tile >> 4;
    transpose_tile64(src, bufU + (size_t)z * DF * HID, rs, HID, tk * 64, tn * 64, smem);
}

// ---------------- D1: T(U) z in [0, ZSPLIT): grid(512, ZSPLIT) ----------------
__global__ __launch_bounds__(256)
void tu_head_kernel(const float* __restrict__ w_up, const float* __restrict__ sh_up,
                    unsigned short* __restrict__ bufU) {
    __shared__ __align__(16) char smem[16640];
    tu_tile(blockIdx.y, blockIdx.x, w_up, sh_up, bufU, smem);
}

// ---------------- up-GEMM body (round-7-verified single-buffer), smem passed in ----------------
static __device__ void gemm_up_body(int bx, int by, int bz,
                                    const unsigned short* __restrict__ xb,
                                    const unsigned short* __restrict__ bufU,
                                    unsigned short* __restrict__ act,
                                    const int* __restrict__ offsets,
                                    const int* __restrict__ perm,
                                    const float* __restrict__ pw, char* lds) {
    constexpr int K = HID, N = DF;
    char* As = lds;
    char* Bs = lds + 16384;

    int tid = threadIdx.x;
    int lane = tid & 63, wvid = tid >> 6, wr = wvid >> 1, wc = wvid & 1;

    int off = offsets[bz], end = offsets[bz + 1];
    int row0 = off + by * 128;
    if (row0 >= end) return;
    int n0 = bx * 128;

    int lr = lane >> 3;
    int csrc = (((lane & 7) ^ lr) << 4);
    size_t abyte[4], bbyte[4];
    int ldsoff[4];
    const char* Bb = (const char*)bufU + (size_t)bz * ((size_t)N * K * 2);
    #pragma unroll
    for (int p = 0; p < 4; ++p) {
        int r = p * 32 + wvid * 8 + lr;
        int gr = row0 + r;
        if (gr > end - 1) gr = end - 1;
        abyte[p] = (size_t)perm[gr] * (K * 2);
        bbyte[p] = (size_t)(n0 + r) * (K * 2);
        ldsoff[p] = (p * 32 + wvid * 8) * 128;
    }

    f32x4 acc[4][4] = {};
    for (int k0 = 0; k0 < K; k0 += 64) {
        __syncthreads();
        #pragma unroll
        for (int p = 0; p < 4; ++p) {
            gload16((const char*)xb + abyte[p] + k0 * 2 + csrc, As + ldsoff[p]);
            gload16(Bb + bbyte[p] + k0 * 2 + csrc, Bs + ldsoff[p]);
        }
        __syncthreads();
        #pragma unroll
        for (int ks = 0; ks < 2; ++ks) {
            int kg = lane >> 4, r16 = lane & 15;
            short8 af[4], bfr[4];
            #pragma unroll
            for (int m = 0; m < 4; ++m) {
                int r = wr * 64 + m * 16 + r16;
                af[m] = *(const short8*)(As + r * 128 + ((ks * 64 + kg * 16) ^ ((r & 7) << 4)));
            }
            #pragma unroll
            for (int n = 0; n < 4; ++n) {
                int c = wc * 64 + n * 16 + r16;
                bfr[n] = *(const short8*)(Bs + c * 128 + ((ks * 64 + kg * 16) ^ ((c & 7) << 4)));
            }
            #pragma unroll
            for (int m = 0; m < 4; ++m)
                #pragma unroll
                for (int n = 0; n < 4; ++n)
                    acc[m][n] = __builtin_amdgcn_mfma_f32_16x16x32_bf16(af[m], bfr[n], acc[m][n], 0, 0, 0);
        }
    }

    int r16 = lane & 15, rg = lane >> 4;
    #pragma unroll
    for (int m = 0; m < 4; ++m) {
        #pragma unroll
        for (int j = 0; j < 4; ++j) {
            int rr = row0 + wr * 64 + m * 16 + rg * 4 + j;
            if (rr < end) {
                float scale = pw[rr];
                #pragma unroll
                for (int n = 0; n < 4; ++n) {
                    int cc = n0 + wc * 64 + n * 16 + r16;
                    float v = acc[m][n][j];
                    v = v > 0.f ? v * v : 0.f;
                    act[(size_t)rr * N + cc] = f2b(v * scale);
                }
            }
        }
    }
}

// ---------------- D2: up-GEMM z<ZSPLIT (1536, bid%9==0) + T(U) z>=ZSPLIT (12288 tiles) ----
__global__ __launch_bounds__(256, 2)
void d2_kernel(const unsigned short* __restrict__ xb,
               const unsigned short* __restrict__ bufU_ro,
               unsigned short* __restrict__ act,
               const int* __restrict__ offsets, const int* __restrict__ perm,
               const float* __restrict__ pw,
               const float* __restrict__ w_up, const float* __restrict__ sh_up,
               unsigned short* __restrict__ bufU_wr) {
    __shared__ __align__(16) char smem[32768];
    int bid = blockIdx.x;
    if (bid % 9 != 0) {
        int tile = bid - bid / 9 - 1;             // 0..12287
        int tz = ZSPLIT + (tile >> 9);            // 12..35
        tu_tile(tz, tile & 511, w_up, sh_up, bufU_wr, smem);
        return;
    }
    int g = bid / 9;                              // 0..1535 over z in [0,ZSPLIT)
    gemm_up_body(g & 7, (g >> 3) & 15, g >> 7, xb, bufU_ro, act, offsets, perm, pw, smem);
}

// ---------------- D3: up-GEMM z>=ZSPLIT (3072, bid%7==0) + T(D) all (18432 tiles) ----
__global__ __launch_bounds__(256, 2)
void d3_kernel(const unsigned short* __restrict__ xb,
               const unsigned short* __restrict__ bufU,
               unsigned short* __restrict__ act,
               const int* __restrict__ offsets, const int* __restrict__ perm,
               const float* __restrict__ pw,
               const float* __restrict__ w_dn, const float* __restrict__ sh_dn,
               unsigned short* __restrict__ bufD) {
    __shared__ __align__(16) char smem[32768];
    int bid = blockIdx.x;
    if (bid % 7 != 0) {
        int tile = bid - bid / 7 - 1;             // 0..18431
        int tz = tile >> 9;                       // 0..35
        int rem = tile & 511;
        int tn = rem & 31, tk = rem >> 5;         // N=2048: 32, K=1024: 16
        const float* src = (tz < NE) ? (w_dn + (size_t)tz * DF * HID)
                                     : (sh_dn + (size_t)(tz - NE) * DF * HID);
        transpose_tile64(src, bufD + (size_t)tz * HID * DF, HID, DF, tk * 64, tn * 64, smem);
        return;
    }
    int g = bid / 7;                              // 0..3071 over z in [ZSPLIT, 36)
    gemm_up_body(g & 7, (g >> 3) & 15, ZSPLIT + (g >> 7), xb, bufU, act, offsets, perm, pw, smem);
}

// ---------------- down-GEMM (R14-exact): z=0..35, K=1024, N=2048; C=slotout bf16 ----
__global__ __launch_bounds__(256, 2)
void gemm_down_kernel(const unsigned short* __restrict__ act, const unsigned short* __restrict__ bufD,
                      unsigned short* __restrict__ slotout, const int* __restrict__ offsets) {
    constexpr int K = DF, N = HID;
    __shared__ __align__(16) char lds[32768];
    char* As = lds;
    char* Bs = lds + 16384;

    int tid = threadIdx.x;
    int lane = tid & 63, wvid = tid >> 6, wr = wvid >> 1, wc = wvid & 1;

    int bz = blockIdx.z;
    int off = offsets[bz], end = offsets[bz + 1];
    int row0 = off + blockIdx.y * 128;
    if (row0 >= end) return;
    int n0 = blockIdx.x * 128;

    int lr = lane >> 3;
    int csrc = (((lane & 7) ^ lr) << 4);
    size_t abyte[4], bbyte[4];
    int ldsoff[4];
    const char* Bb = (const char*)bufD + (size_t)bz * ((size_t)N * K * 2);
    #pragma unroll
    for (int p = 0; p < 4; ++p) {
        int r = p * 32 + wvid * 8 + lr;
        int gr = row0 + r;
        if (gr > end - 1) gr = end - 1;
        abyte[p] = (size_t)gr * (K * 2);
        bbyte[p] = (size_t)(n0 + r) * (K * 2);
        ldsoff[p] = (p * 32 + wvid * 8) * 128;
    }

    f32x4 acc[4][4] = {};
    for (int k0 = 0; k0 < K; k0 += 64) {
        __syncthreads();
        #pragma unroll
        for (int p = 0; p < 4; ++p) {
            gload16((const char*)act + abyte[p] + k0 * 2 + csrc, As + ldsoff[p]);
            gload16(Bb + bbyte[p] + k0 * 2 + csrc, Bs + ldsoff[p]);
        }
        __syncthreads();
        #pragma unroll
        for (int ks = 0; ks < 2; ++ks) {
            int kg = lane >> 4, r16 = lane & 15;
            short8 af[4], bfr[4];
            #pragma unroll
            for (int m = 0; m < 4; ++m) {
                int r = wr * 64 + m * 16 + r16;
                af[m] = *(const short8*)(As + r * 128 + ((ks * 64 + kg * 16) ^ ((r & 7) << 4)));
            }
            #pragma unroll
            for (int n = 0; n < 4; ++n) {
                int c = wc * 64 + n * 16 + r16;
                bfr[n] = *(const short8*)(Bs + c * 128 + ((ks * 64 + kg * 16) ^ ((c & 7) << 4)));
            }
            #pragma unroll
            for (int m = 0; m < 4; ++m)
                #pragma unroll
                for (int n = 0; n < 4; ++n)
                    acc[m][n] = __builtin_amdgcn_mfma_f32_16x16x32_bf16(af[m], bfr[n], acc[m][n], 0, 0, 0);
        }
    }

    int r16 = lane & 15, rg = lane >> 4;
    #pragma unroll
    for (int m = 0; m < 4; ++m) {
        #pragma unroll
        for (int j = 0; j < 4; ++j) {
            int rr = row0 + wr * 64 + m * 16 + rg * 4 + j;
            if (rr < end) {
                #pragma unroll
                for (int n = 0; n < 4; ++n) {
                    int cc = n0 + wc * 64 + n * 16 + r16;
                    slotout[(size_t)rr * N + cc] = f2b(acc[m][n][j]);
                }
            }
        }
    }
}

// ---------------- combine: out[t] = sum of 6 routed + 4 shared slot rows (bf16 in, f32 out) ----
__global__ void combine_kernel(const unsigned short* __restrict__ slotout,
                               const int* __restrict__ slot_of,
                               float* __restrict__ out) {
    int t = blockIdx.x, tid = threadIdx.x;
    int s[10];
    #pragma unroll
    for (int k = 0; k < TOPK; ++k) s[k] = slot_of[t * TOPK + k];
    #pragma unroll
    for (int j = 0; j < 4; ++j) s[TOPK + j] = 12288 + j * T_TOK + t;
    int c = tid * 8;
    float a[8] = {0.f, 0.f, 0.f, 0.f, 0.f, 0.f, 0.f, 0.f};
    #pragma unroll
    for (int k = 0; k < 10; ++k) {
        short8 v = *(const short8*)(slotout + (size_t)s[k] * HID + c);
        #pragma unroll
        for (int i = 0; i < 8; ++i) a[i] += b2f((unsigned short)v[i]);
    }
    *(float4*)(out + (size_t)t * HID + c) = make_float4(a[0], a[1], a[2], a[3]);
    *(float4*)(out + (size_t)t * HID + c + 4) = make_float4(a[4], a[5], a[6], a[7]);
}

extern "C" void kernel_launch(void* const* d_in, const int* in_sizes, int n_in,
                              void* d_out, int out_size, void* d_ws, size_t ws_size,
                              hipStream_t stream) {
    const float* x     = (const float*)d_in[0];
    const float* rw    = (const float*)d_in[1];
    const float* rb    = (const float*)d_in[2];
    const float* w_up  = (const float*)d_in[3];
    const float* w_dn  = (const float*)d_in[4];
    const float* sh_up = (const float*)d_in[5];
    const float* sh_dn = (const float*)d_in[6];
    float* out = (float*)d_out;
    char* ws = (char*)d_ws;

    int*   counts  = (int*)(ws);
    int*   cursors = (int*)(ws + 128);
    int*   offsets = (int*)(ws + 256);            // 37 ints
    int*   tidx    = (int*)(ws + 1024);           // 12288 int
    float* tw      = (float*)(ws + 50176);        // 12288 f32
    int*   slot_of = (int*)(ws + 99328);          // 12288 int
    int*   perm    = (int*)(ws + 148480);         // 20480 int
    float* pw      = (float*)(ws + 230400);       // 20480 f32
    unsigned short* xb   = (unsigned short*)(ws + 312320);     // [2048][2048] bf16 (8.4MB)
    unsigned short* act  = (unsigned short*)(ws + 8700928);    // [20480][1024] bf16 (41.9MB)
    unsigned short* bufU = (unsigned short*)(ws + 50643968);   // 36x[1024][2048] bf16 (151MB)
    unsigned short* bufD = (unsigned short*)(ws + 201638912);  // 36x[2048][1024] bf16 (151MB)
    unsigned short* slotout = (unsigned short*)(ws + 352633856); // [20480][2048] bf16 (84MB)

    hipMemsetAsync(ws, 0, 256, stream);  // counts + cursors

    router_kernel<<<T_TOK, 256, 0, stream>>>(x, rw, rb, tidx, tw, counts, xb);
    scan_kernel<<<1, 64, 0, stream>>>(counts, offsets);
    scatter_kernel<<<(T_TOK + 255) / 256, 256, 0, stream>>>(tidx, tw, offsets, cursors,
                                                            perm, pw, slot_of);

    // D1: T(U) head (z < ZSPLIT)
    tu_head_kernel<<<dim3(512, ZSPLIT), 256, 0, stream>>>(w_up, sh_up, bufU);

    // D2: up-GEMM z<ZSPLIT (1536, bid%9==0) packed with T(U) tail (12288 tiles)
    d2_kernel<<<13824, 256, 0, stream>>>(xb, bufU, act, offsets, perm, pw,
                                         w_up, sh_up, bufU);

    // D3: up-GEMM z>=ZSPLIT (3072, bid%7==0) packed with T(D) all (18432 tiles)
    d3_kernel<<<21504, 256, 0, stream>>>(xb, bufU, act, offsets, perm, pw,
                                         w_dn, sh_dn, bufD);

    // down-GEMM (R14-exact dim3 grid)
    gemm_down_kernel<<<dim3(HID / 128, T_TOK / 128, EXT_E), 256, 0, stream>>>(
        act, bufD, slotout, offsets);

    combine_kernel<<<T_TOK, 256, 0, stream>>>(slotout, slot_of, out);
}

// Round 18
// 564.291 us; speedup vs baseline: 1.4091x; 1.1322x over previous
//
#include <hip/hip_runtime.h>
#include <hip/hip_bf16.h>
#include <math.h>

#define T_TOK 2048
#define HID   2048
#define NE    32
#define DF    1024
#define DSZ   4096
#define TOPK  6
#define NGRP  8
#define TOPKG 4
#define RSCALE 2.5f
#define EXT_E 36            // 32 routed + 4 shared pseudo-experts
#define NSLOT 20480         // 12288 routed + 8192 shared slots

typedef __attribute__((ext_vector_type(8))) short short8;
typedef __attribute__((ext_vector_type(4))) float f32x4;

typedef __attribute__((address_space(1))) const void gv1;
typedef __attribute__((address_space(3))) void lv3;

static __device__ __forceinline__ void gload16(const void* g, void* l) {
    __builtin_amdgcn_global_load_lds((gv1*)g, (lv3*)l, 16, 0, 0);
}

static __device__ __forceinline__ unsigned short f2b(float f) {
    union { float f; unsigned u; } v; v.f = f;
    unsigned r = v.u + 0x7fffu + ((v.u >> 16) & 1u);
    return (unsigned short)(r >> 16);
}

static __device__ __forceinline__ float b2f(unsigned short b) {
    union { float f; unsigned u; } v; v.u = ((unsigned)b) << 16;
    return v.f;
}

// ---------------- router (one block per token), fused x->bf16 ----------------
__global__ __launch_bounds__(256)
void router_kernel(const float* __restrict__ x, const float* __restrict__ rw,
                   const float* __restrict__ rb,
                   int* __restrict__ tidx, float* __restrict__ tw,
                   int* __restrict__ counts, unsigned short* __restrict__ xb) {
    __shared__ float xs[HID];
    __shared__ float part[256];
    __shared__ float scores[NE];
    __shared__ float sfc[NE];
    int t = blockIdx.x;
    int tid = threadIdx.x;
    for (int i = tid; i < HID / 4; i += 256) {
        ((float4*)xs)[i] = ((const float4*)(x + (size_t)t * HID))[i];
    }
    __syncthreads();
    {
        float4 a = ((const float4*)xs)[tid * 2];
        float4 b = ((const float4*)xs)[tid * 2 + 1];
        short8 o;
        o[0] = (short)f2b(a.x); o[1] = (short)f2b(a.y); o[2] = (short)f2b(a.z); o[3] = (short)f2b(a.w);
        o[4] = (short)f2b(b.x); o[5] = (short)f2b(b.y); o[6] = (short)f2b(b.z); o[7] = (short)f2b(b.w);
        *(short8*)(xb + (size_t)t * HID + tid * 8) = o;
    }
    int e = tid & 31, ch = tid >> 5;
    const float* w = rw + (size_t)e * HID + ch * 256;
    const float* xv = xs + ch * 256;
    float p = 0.f;
    #pragma unroll 8
    for (int k = 0; k < 256; ++k) p += xv[k] * w[k];
    part[tid] = p;
    __syncthreads();
    if (tid < 32) {
        float l = 0.f;
        #pragma unroll
        for (int c = 0; c < 8; ++c) l += part[c * 32 + tid];
        float s = 1.f / (1.f + expf(-l));
        scores[tid] = s;
        sfc[tid] = s + rb[tid];
    }
    __syncthreads();
    if (tid == 0) {
        float gs[NGRP];
        for (int g = 0; g < NGRP; ++g) {
            float v[4];
            for (int i = 0; i < 4; ++i) v[i] = sfc[g * 4 + i];
            int bi = 0;
            for (int i = 1; i < 4; ++i) if (v[i] > v[bi]) bi = i;
            float m1 = v[bi]; v[bi] = -INFINITY;
            int bj = 0;
            for (int i = 1; i < 4; ++i) if (v[i] > v[bj]) bj = i;
            gs[g] = m1 + v[bj];
        }
        bool gsel[NGRP];
        for (int g = 0; g < NGRP; ++g) gsel[g] = false;
        for (int k = 0; k < TOPKG; ++k) {
            int bi = -1; float b = -INFINITY;
            for (int g = 0; g < NGRP; ++g)
                if (!gsel[g] && gs[g] > b) { b = gs[g]; bi = g; }
            gsel[bi] = true;
        }
        float masked[NE];
        for (int i = 0; i < NE; ++i) masked[i] = gsel[i >> 2] ? sfc[i] : 0.0f;
        int sel[TOPK]; float wv[TOPK]; float wsum = 0.f;
        for (int k = 0; k < TOPK; ++k) {
            int bi = -1; float b = -INFINITY;
            for (int i = 0; i < NE; ++i)
                if (masked[i] > b) { b = masked[i]; bi = i; }
            masked[bi] = -INFINITY;
            sel[k] = bi; wv[k] = scores[bi]; wsum += wv[k];
        }
        float inv = RSCALE / (wsum + 1e-20f);
        for (int k = 0; k < TOPK; ++k) {
            tidx[t * TOPK + k] = sel[k];
            tw[t * TOPK + k] = wv[k] * inv;
            atomicAdd(&counts[sel[k]], 1);
        }
    }
}

__global__ void scan_kernel(const int* __restrict__ counts, int* __restrict__ offsets) {
    if (threadIdx.x == 0) {
        int a = 0;
        for (int e2 = 0; e2 < NE; ++e2) { offsets[e2] = a; a += counts[e2]; }
        offsets[NE] = a;                          // = 12288
        for (int j = 1; j <= 4; ++j) offsets[NE + j] = 12288 + j * T_TOK;
    }
}

__global__ void scatter_kernel(const int* __restrict__ tidx, const float* __restrict__ tw,
                               const int* __restrict__ offsets, int* __restrict__ cursors,
                               int* __restrict__ perm, float* __restrict__ pw,
                               int* __restrict__ slot_of) {
    int t = blockIdx.x * blockDim.x + threadIdx.x;
    if (t >= T_TOK) return;
    for (int k = 0; k < TOPK; ++k) {
        int e = tidx[t * TOPK + k];
        int pos = atomicAdd(&cursors[e], 1);
        int slot = offsets[e] + pos;
        perm[slot] = t;
        pw[slot] = tw[t * TOPK + k];
        slot_of[t * TOPK + k] = slot;
    }
    #pragma unroll
    for (int j = 0; j < 4; ++j) {                 // shared pseudo-expert slots
        int slot = 12288 + j * T_TOK + t;
        perm[slot] = t;
        pw[slot] = 1.0f;
    }
}

// ---------------- transpose v4 tile body (round-7-measured), smem passed in ----------------
static __device__ __forceinline__ void transpose_tile64(
        const float* __restrict__ src, unsigned short* __restrict__ dst,
        int rs, int Kd, int k0, int n0, char* smem) {
    float (*tl)[65] = (float(*)[65])smem;
    int t = threadIdx.x;
    int r0 = t >> 4;             // 0..15
    int c4 = (t & 15) * 4;       // 0..60
    #pragma unroll
    for (int p = 0; p < 4; ++p) {
        int r = r0 + p * 16;
        float4 v = *(const float4*)(src + (size_t)(k0 + r) * rs + n0 + c4);
        tl[c4 + 0][r] = v.x;
        tl[c4 + 1][r] = v.y;
        tl[c4 + 2][r] = v.z;
        tl[c4 + 3][r] = v.w;
    }
    __syncthreads();
    int n = t >> 2;              // 0..63
    int kq = (t & 3) * 16;       // 0..48
    unsigned short o[16];
    #pragma unroll
    for (int i = 0; i < 16; ++i) o[i] = f2b(tl[n][kq + i]);
    unsigned short* d = dst + (size_t)(n0 + n) * Kd + k0 + kq;
    *(short8*)(d) = *(short8*)&o[0];
    *(short8*)(d + 8) = *(short8*)&o[8];
}

// ---------------- T(U) standalone: grid(512, 36) ----------------
__global__ __launch_bounds__(256)
void transpose_up_kernel(const float* __restrict__ w_up, const float* __restrict__ sh_up,
                         unsigned short* __restrict__ bufU) {
    __shared__ __align__(16) char smem[16640];
    int z = blockIdx.y;
    const float* src; int rs;
    if (z < NE) { src = w_up + (size_t)z * HID * DF; rs = DF; }
    else        { src = sh_up + (size_t)(z - NE) * DF; rs = DSZ; }
    int tile = blockIdx.x;
    int tn = tile & 15, tk = tile >> 4;           // N=1024: 16, K=2048: 32
    transpose_tile64(src, bufU + (size_t)z * DF * HID, rs, HID, tk * 64, tn * 64, smem);
}

// ---------------- up-GEMM body (round-7-verified single-buffer), smem passed in ----------------
static __device__ void gemm_up_body(int bx, int by, int bz,
                                    const unsigned short* __restrict__ xb,
                                    const unsigned short* __restrict__ bufU,
                                    unsigned short* __restrict__ act,
                                    const int* __restrict__ offsets,
                                    const int* __restrict__ perm,
                                    const float* __restrict__ pw, char* lds) {
    constexpr int K = HID, N = DF;
    char* As = lds;
    char* Bs = lds + 16384;

    int tid = threadIdx.x;
    int lane = tid & 63, wvid = tid >> 6, wr = wvid >> 1, wc = wvid & 1;

    int off = offsets[bz], end = offsets[bz + 1];
    int row0 = off + by * 128;
    if (row0 >= end) return;
    int n0 = bx * 128;

    int lr = lane >> 3;
    int csrc = (((lane & 7) ^ lr) << 4);
    size_t abyte[4], bbyte[4];
    int ldsoff[4];
    const char* Bb = (const char*)bufU + (size_t)bz * ((size_t)N * K * 2);
    #pragma unroll
    for (int p = 0; p < 4; ++p) {
        int r = p * 32 + wvid * 8 + lr;
        int gr = row0 + r;
        if (gr > end - 1) gr = end - 1;
        abyte[p] = (size_t)perm[gr] * (K * 2);
        bbyte[p] = (size_t)(n0 + r) * (K * 2);
        ldsoff[p] = (p * 32 + wvid * 8) * 128;
    }

    f32x4 acc[4][4] = {};
    for (int k0 = 0; k0 < K; k0 += 64) {
        __syncthreads();
        #pragma unroll
        for (int p = 0; p < 4; ++p) {
            gload16((const char*)xb + abyte[p] + k0 * 2 + csrc, As + ldsoff[p]);
            gload16(Bb + bbyte[p] + k0 * 2 + csrc, Bs + ldsoff[p]);
        }
        __syncthreads();
        #pragma unroll
        for (int ks = 0; ks < 2; ++ks) {
            int kg = lane >> 4, r16 = lane & 15;
            short8 af[4], bfr[4];
            #pragma unroll
            for (int m = 0; m < 4; ++m) {
                int r = wr * 64 + m * 16 + r16;
                af[m] = *(const short8*)(As + r * 128 + ((ks * 64 + kg * 16) ^ ((r & 7) << 4)));
            }
            #pragma unroll
            for (int n = 0; n < 4; ++n) {
                int c = wc * 64 + n * 16 + r16;
                bfr[n] = *(const short8*)(Bs + c * 128 + ((ks * 64 + kg * 16) ^ ((c & 7) << 4)));
            }
            #pragma unroll
            for (int m = 0; m < 4; ++m)
                #pragma unroll
                for (int n = 0; n < 4; ++n)
                    acc[m][n] = __builtin_amdgcn_mfma_f32_16x16x32_bf16(af[m], bfr[n], acc[m][n], 0, 0, 0);
        }
    }

    int r16 = lane & 15, rg = lane >> 4;
    #pragma unroll
    for (int m = 0; m < 4; ++m) {
        #pragma unroll
        for (int j = 0; j < 4; ++j) {
            int rr = row0 + wr * 64 + m * 16 + rg * 4 + j;
            if (rr < end) {
                float scale = pw[rr];
                #pragma unroll
                for (int n = 0; n < 4; ++n) {
                    int cc = n0 + wc * 64 + n * 16 + r16;
                    float v = acc[m][n][j];
                    v = v > 0.f ? v * v : 0.f;
                    act[(size_t)rr * N + cc] = f2b(v * scale);
                }
            }
        }
    }
}

// ---------------- merged: up-GEMM (bid%5==0, 4608) + T(D) (18432 tiles) ----------------
// T(D) writes bufD (read only by NEXT dispatch); up-GEMM reads xb/bufU (prior dispatches).
__global__ __launch_bounds__(256, 2)
void gemm_up_tdn_kernel(const unsigned short* __restrict__ xb,
                        const unsigned short* __restrict__ bufU,
                        unsigned short* __restrict__ act,
                        const int* __restrict__ offsets, const int* __restrict__ perm,
                        const float* __restrict__ pw,
                        const float* __restrict__ w_dn, const float* __restrict__ sh_dn,
                        unsigned short* __restrict__ bufD) {
    __shared__ __align__(16) char smem[32768];
    int bid = blockIdx.x;
    if (bid % 5 != 0) {
        int tile = bid - bid / 5 - 1;             // 0..18431
        int tz = tile >> 9;                       // 0..35
        int rem = tile & 511;
        int tn = rem & 31, tk = rem >> 5;         // N=2048: 32, K=1024: 16
        const float* src = (tz < NE) ? (w_dn + (size_t)tz * DF * HID)
                                     : (sh_dn + (size_t)(tz - NE) * DF * HID);
        transpose_tile64(src, bufD + (size_t)tz * HID * DF, HID, DF, tk * 64, tn * 64, smem);
        return;
    }
    int g = bid / 5;                              // 0..4607
    gemm_up_body(g & 7, (g >> 3) & 15, g >> 7, xb, bufU, act, offsets, perm, pw, smem);
}

// ---------------- down-GEMM (round-7-verified): z=0..35, K=1024, N=2048; C=slotout bf16 ----
__global__ __launch_bounds__(256, 2)
void gemm_down_kernel(const unsigned short* __restrict__ act, const unsigned short* __restrict__ bufD,
                      unsigned short* __restrict__ slotout, const int* __restrict__ offsets) {
    constexpr int K = DF, N = HID;
    __shared__ __align__(16) char lds[32768];
    char* As = lds;
    char* Bs = lds + 16384;

    int tid = threadIdx.x;
    int lane = tid & 63, wvid = tid >> 6, wr = wvid >> 1, wc = wvid & 1;

    int bz = blockIdx.z;
    int off = offsets[bz], end = offsets[bz + 1];
    int row0 = off + blockIdx.y * 128;
    if (row0 >= end) return;
    int n0 = blockIdx.x * 128;

    int lr = lane >> 3;
    int csrc = (((lane & 7) ^ lr) << 4);
    size_t abyte[4], bbyte[4];
    int ldsoff[4];
    const char* Bb = (const char*)bufD + (size_t)bz * ((size_t)N * K * 2);
    #pragma unroll
    for (int p = 0; p < 4; ++p) {
        int r = p * 32 + wvid * 8 + lr;
        int gr = row0 + r;
        if (gr > end - 1) gr = end - 1;
        abyte[p] = (size_t)gr * (K * 2);
        bbyte[p] = (size_t)(n0 + r) * (K * 2);
        ldsoff[p] = (p * 32 + wvid * 8) * 128;
    }

    f32x4 acc[4][4] = {};
    for (int k0 = 0; k0 < K; k0 += 64) {
        __syncthreads();
        #pragma unroll
        for (int p = 0; p < 4; ++p) {
            gload16((const char*)act + abyte[p] + k0 * 2 + csrc, As + ldsoff[p]);
            gload16(Bb + bbyte[p] + k0 * 2 + csrc, Bs + ldsoff[p]);
        }
        __syncthreads();
        #pragma unroll
        for (int ks = 0; ks < 2; ++ks) {
            int kg = lane >> 4, r16 = lane & 15;
            short8 af[4], bfr[4];
            #pragma unroll
            for (int m = 0; m < 4; ++m) {
                int r = wr * 64 + m * 16 + r16;
                af[m] = *(const short8*)(As + r * 128 + ((ks * 64 + kg * 16) ^ ((r & 7) << 4)));
            }
            #pragma unroll
            for (int n = 0; n < 4; ++n) {
                int c = wc * 64 + n * 16 + r16;
                bfr[n] = *(const short8*)(Bs + c * 128 + ((ks * 64 + kg * 16) ^ ((c & 7) << 4)));
            }
            #pragma unroll
            for (int m = 0; m < 4; ++m)
                #pragma unroll
                for (int n = 0; n < 4; ++n)
                    acc[m][n] = __builtin_amdgcn_mfma_f32_16x16x32_bf16(af[m], bfr[n], acc[m][n], 0, 0, 0);
        }
    }

    int r16 = lane & 15, rg = lane >> 4;
    #pragma unroll
    for (int m = 0; m < 4; ++m) {
        #pragma unroll
        for (int j = 0; j < 4; ++j) {
            int rr = row0 + wr * 64 + m * 16 + rg * 4 + j;
            if (rr < end) {
                #pragma unroll
                for (int n = 0; n < 4; ++n) {
                    int cc = n0 + wc * 64 + n * 16 + r16;
                    slotout[(size_t)rr * N + cc] = f2b(acc[m][n][j]);
                }
            }
        }
    }
}

// ---------------- combine: out[t] = sum of 6 routed + 4 shared slot rows (bf16 in, f32 out) ----
__global__ void combine_kernel(const unsigned short* __restrict__ slotout,
                               const int* __restrict__ slot_of,
                               float* __restrict__ out) {
    int t = blockIdx.x, tid = threadIdx.x;
    int s[10];
    #pragma unroll
    for (int k = 0; k < TOPK; ++k) s[k] = slot_of[t * TOPK + k];
    #pragma unroll
    for (int j = 0; j < 4; ++j) s[TOPK + j] = 12288 + j * T_TOK + t;
    int c = tid * 8;
    float a[8] = {0.f, 0.f, 0.f, 0.f, 0.f, 0.f, 0.f, 0.f};
    #pragma unroll
    for (int k = 0; k < 10; ++k) {
        short8 v = *(const short8*)(slotout + (size_t)s[k] * HID + c);
        #pragma unroll
        for (int i = 0; i < 8; ++i) a[i] += b2f((unsigned short)v[i]);
    }
    *(float4*)(out + (size_t)t * HID + c) = make_float4(a[0], a[1], a[2], a[3]);
    *(float4*)(out + (size_t)t * HID + c + 4) = make_float4(a[4], a[5], a[6], a[7]);
}

extern "C" void kernel_launch(void* const* d_in, const int* in_sizes, int n_in,
                              void* d_out, int out_size, void* d_ws, size_t ws_size,
                              hipStream_t stream) {
    const float* x     = (const float*)d_in[0];
    const float* rw    = (const float*)d_in[1];
    const float* rb    = (const float*)d_in[2];
    const float* w_up  = (const float*)d_in[3];
    const float* w_dn  = (const float*)d_in[4];
    const float* sh_up = (const float*)d_in[5];
    const float* sh_dn = (const float*)d_in[6];
    float* out = (float*)d_out;
    char* ws = (char*)d_ws;

    int*   counts  = (int*)(ws);
    int*   cursors = (int*)(ws + 128);
    int*   offsets = (int*)(ws + 256);            // 37 ints
    int*   tidx    = (int*)(ws + 1024);           // 12288 int
    float* tw      = (float*)(ws + 50176);        // 12288 f32
    int*   slot_of = (int*)(ws + 99328);          // 12288 int
    int*   perm    = (int*)(ws + 148480);         // 20480 int
    float* pw      = (float*)(ws + 230400);       // 20480 f32
    unsigned short* xb   = (unsigned short*)(ws + 312320);     // [2048][2048] bf16 (8.4MB)
    unsigned short* act  = (unsigned short*)(ws + 8700928);    // [20480][1024] bf16 (41.9MB)
    unsigned short* bufU = (unsigned short*)(ws + 50643968);   // 36x[1024][2048] bf16 (151MB)
    unsigned short* bufD = (unsigned short*)(ws + 201638912);  // 36x[2048][1024] bf16 (151MB)
    unsigned short* slotout = (unsigned short*)(ws + 352633856); // [20480][2048] bf16 (84MB)

    hipMemsetAsync(ws, 0, 256, stream);  // counts + cursors

    router_kernel<<<T_TOK, 256, 0, stream>>>(x, rw, rb, tidx, tw, counts, xb);
    scan_kernel<<<1, 64, 0, stream>>>(counts, offsets);
    scatter_kernel<<<(T_TOK + 255) / 256, 256, 0, stream>>>(tidx, tw, offsets, cursors,
                                                            perm, pw, slot_of);

    // T(U) standalone
    transpose_up_kernel<<<dim3(512, EXT_E), 256, 0, stream>>>(w_up, sh_up, bufU);

    // up-GEMM (4608, bid%5==0) packed with T(D) (18432 tiles)
    gemm_up_tdn_kernel<<<23040, 256, 0, stream>>>(xb, bufU, act, offsets, perm, pw,
                                                  w_dn, sh_dn, bufD);

    gemm_down_kernel<<<dim3(HID / 128, T_TOK / 128, EXT_E), 256, 0, stream>>>(
        act, bufD, slotout, offsets);

    combine_kernel<<<T_TOK, 256, 0, stream>>>(slotout, slot_of, out);
}